// Round 1
// baseline (4250.706 us; speedup 1.0000x reference)
//
// MoCA fused pipeline — round 1: correct fp32 baseline, strip-tiled to fit ws.
// Stages: conv3 (C1=conv_x, C2=conv_xT in [s,d] layout, C4=conv_g) ->
//   per s-strip: G=x@xT (NT), A=C1@C2T (NT), softmax over batch (axis 0),
//   moca 5x5 conv on {G_sm, A_sm}, Wz = M @ C4 + x.
#include <hip/hip_runtime.h>

#define Bz 8
#define Sz 2048
#define Dz 1024

// ---------------- fused 5x5 convs over x ----------------
// C1[s,d] = sum w1[i,j] x[s+i-2, d+j-2] + b1
// C2[s,d] = sum w2[j,i] x[s+i-2, d+j-2] + b2   (== conv_xT[b,d,s] transposed into [s,d])
// C4[s,d] = sum w4[i,j] x[s+i-2, d+j-2] + b4
__global__ __launch_bounds__(256) void conv3_kernel(
    const float* __restrict__ x,
    const float* __restrict__ w1, const float* __restrict__ b1,
    const float* __restrict__ w2, const float* __restrict__ b2,
    const float* __restrict__ w4, const float* __restrict__ b4,
    float* __restrict__ C1, float* __restrict__ C2, float* __restrict__ C4)
{
    __shared__ float w[75];
    __shared__ float bias[3];
    int tid = threadIdx.x;
    if (tid < 25) w[tid] = w1[tid];
    else if (tid < 50) w[tid] = w2[tid - 25];
    else if (tid < 75) w[tid] = w4[tid - 50];
    if (tid == 75) { bias[0] = b1[0]; bias[1] = b2[0]; bias[2] = b4[0]; }
    __syncthreads();

    int d = blockIdx.x * 256 + tid;   // 0..1023
    int s = blockIdx.y;
    int b = blockIdx.z;
    const float* xb = x + (size_t)b * Sz * Dz;

    float a1 = 0.f, a2 = 0.f, a4 = 0.f;
#pragma unroll
    for (int i = 0; i < 5; i++) {
        int ss = s + i - 2;
        bool sv = (ss >= 0 && ss < Sz);
#pragma unroll
        for (int j = 0; j < 5; j++) {
            int dd = d + j - 2;
            float v = (sv && dd >= 0 && dd < Dz) ? xb[(size_t)ss * Dz + dd] : 0.f;
            a1 += w[i * 5 + j] * v;
            a2 += w[25 + j * 5 + i] * v;   // transposed kernel
            a4 += w[50 + i * 5 + j] * v;
        }
    }
    size_t o = (size_t)b * Sz * Dz + (size_t)s * Dz + d;
    C1[o] = a1 + bias[0];
    C2[o] = a2 + bias[1];
    C4[o] = a4 + bias[2];
}

// ---------------- fp32 tiled GEMM ----------------
// C[m,n] = sum_k A[m,k] * (BT ? B[n,k] : B[k,n])   (+ Src[m,n] if ADD)
// 64x64 tile, K-step 16, 256 threads, 4x4 acc per thread.
template <bool BT, bool ADD>
__global__ __launch_bounds__(256) void gemm_kernel(
    const float* __restrict__ A, const float* __restrict__ Bm,
    const float* __restrict__ Src, float* __restrict__ C,
    int M, int N, int K,
    long sAb, long sBb, long sCb, long sSb)
{
    __shared__ float As[16][68];
    __shared__ float Bs[16][68];

    int b = blockIdx.z;
    A += (size_t)b * sAb;
    Bm += (size_t)b * sBb;
    C += (size_t)b * sCb;
    if (ADD) Src += (size_t)b * sSb;

    int m0 = blockIdx.y * 64, n0 = blockIdx.x * 64;
    int tid = threadIdx.x;
    int tx = tid & 15, ty = tid >> 4;

    // loader indices
    int lr = tid >> 2;            // 0..63 : row within tile
    int lc = (tid & 3) * 4;       // k-chunk base
    int br = tid >> 4;            // 0..15 : k row (NN B load)
    int bc = (tid & 15) * 4;      // n-chunk base (NN B load)

    float acc[4][4] = {};

    for (int k0 = 0; k0 < K; k0 += 16) {
        float4 av = make_float4(0.f, 0.f, 0.f, 0.f);
        if (m0 + lr < M)
            av = *(const float4*)(A + (size_t)(m0 + lr) * K + k0 + lc);
        float4 bv;
        if (BT) bv = *(const float4*)(Bm + (size_t)(n0 + lr) * K + k0 + lc);
        else    bv = *(const float4*)(Bm + (size_t)(k0 + br) * N + n0 + bc);

        __syncthreads();
        As[lc + 0][lr] = av.x; As[lc + 1][lr] = av.y;
        As[lc + 2][lr] = av.z; As[lc + 3][lr] = av.w;
        if (BT) {
            Bs[lc + 0][lr] = bv.x; Bs[lc + 1][lr] = bv.y;
            Bs[lc + 2][lr] = bv.z; Bs[lc + 3][lr] = bv.w;
        } else {
            *(float4*)&Bs[br][bc] = bv;
        }
        __syncthreads();

#pragma unroll
        for (int kk = 0; kk < 16; kk++) {
            float4 a4 = *(const float4*)&As[kk][ty * 4];
            float4 b4 = *(const float4*)&Bs[kk][tx * 4];
            float ar[4] = { a4.x, a4.y, a4.z, a4.w };
            float brr[4] = { b4.x, b4.y, b4.z, b4.w };
#pragma unroll
            for (int i = 0; i < 4; i++)
#pragma unroll
                for (int j = 0; j < 4; j++)
                    acc[i][j] += ar[i] * brr[j];
        }
    }

#pragma unroll
    for (int i = 0; i < 4; i++) {
        int r = m0 + ty * 4 + i;
        if (r < M) {
            float4 v = make_float4(acc[i][0], acc[i][1], acc[i][2], acc[i][3]);
            if (ADD) {
                float4 sv = *(const float4*)(Src + (size_t)r * N + n0 + tx * 4);
                v.x += sv.x; v.y += sv.y; v.z += sv.z; v.w += sv.w;
            }
            *(float4*)(C + (size_t)r * N + n0 + tx * 4) = v;
        }
    }
}

// ---------------- softmax over batch dim (8 planes) ----------------
__global__ __launch_bounds__(256) void softmax_b_kernel(
    float* __restrict__ P, int nElem, long planeStride)
{
    int idx = blockIdx.x * 256 + threadIdx.x;
    if (idx >= nElem) return;
    float v[Bz];
    float mx = -1e30f;
#pragma unroll
    for (int b = 0; b < Bz; b++) { v[b] = P[idx + (size_t)b * planeStride]; mx = fmaxf(mx, v[b]); }
    float sum = 0.f;
#pragma unroll
    for (int b = 0; b < Bz; b++) { v[b] = __expf(v[b] - mx); sum += v[b]; }
    float inv = 1.f / sum;
#pragma unroll
    for (int b = 0; b < Bz; b++) P[idx + (size_t)b * planeStride] = v[b] * inv;
}

// ---------------- moca 5x5 conv over {G_sm, A_sm} strip ----------------
__global__ __launch_bounds__(256) void moca_kernel(
    const float* __restrict__ Gs, const float* __restrict__ Asm,
    const float* __restrict__ w3, const float* __restrict__ b3,
    float* __restrict__ Mout,
    int s0, int rlo, long psIn, long psOut)
{
    __shared__ float w[50];
    __shared__ float bb;
    int tid = threadIdx.x;
    if (tid < 50) w[tid] = w3[tid];
    if (tid == 50) bb = b3[0];
    __syncthreads();

    int t = blockIdx.x * 256 + tid;
    int so = blockIdx.y;            // 0..h-1
    int b = blockIdx.z;
    int s = s0 + so;                // global output row
    const float* Gp = Gs + (size_t)b * psIn;
    const float* Ap = Asm + (size_t)b * psIn;

    float acc = bb;
#pragma unroll
    for (int i = 0; i < 5; i++) {
        int sr = s + i - 2;
        if (sr < 0 || sr >= Sz) continue;
        int lrow = sr - rlo;
#pragma unroll
        for (int j = 0; j < 5; j++) {
            int tt = t + j - 2;
            if (tt < 0 || tt >= Sz) continue;
            size_t off = (size_t)lrow * Sz + tt;
            acc += w[i * 5 + j] * Gp[off] + w[25 + i * 5 + j] * Ap[off];
        }
    }
    Mout[(size_t)b * psOut + (size_t)so * Sz + t] = acc;
}

// ---------------- host ----------------
extern "C" void kernel_launch(void* const* d_in, const int* in_sizes, int n_in,
                              void* d_out, int out_size, void* d_ws, size_t ws_size,
                              hipStream_t stream)
{
    const float* x  = (const float*)d_in[0];
    const float* w1 = (const float*)d_in[1];
    const float* b1 = (const float*)d_in[2];
    const float* w2 = (const float*)d_in[3];
    const float* b2 = (const float*)d_in[4];
    const float* w3 = (const float*)d_in[5];
    const float* b3 = (const float*)d_in[6];
    const float* w4 = (const float*)d_in[7];
    const float* b4 = (const float*)d_in[8];
    float* out = (float*)d_out;

    const size_t SD = (size_t)Sz * Dz;          // 2,097,152 elems
    const size_t cb = (size_t)Bz * SD * 4;      // 67,108,864 bytes per conv buffer

    char* ws = (char*)d_ws;
    float* C1 = (float*)(ws);
    float* C2 = (float*)(ws + cb);
    float* C4 = (float*)(ws + 2 * cb);

    // choose largest strip height h (divides 2048) that fits ws
    int h = 2048;
    for (;;) {
        size_t PS = (size_t)(h + 4) * Sz;                       // G/A strip plane elems
        size_t need = 3 * cb + (2 * (size_t)Bz * PS + (size_t)Bz * h * Sz) * 4;
        if (need <= ws_size || h == 64) break;
        h >>= 1;
    }
    const size_t PS  = (size_t)(h + 4) * Sz;    // per-batch plane stride, G/A strips
    const size_t PSM = (size_t)h * Sz;          // per-batch plane stride, M strip
    float* Gb = (float*)(ws + 3 * cb);
    float* Ab = Gb + (size_t)Bz * PS;
    float* Mb = Ab + (size_t)Bz * PS;

    // Stage 0: the three 5x5 convs over x in one pass
    conv3_kernel<<<dim3(Dz / 256, Sz, Bz), 256, 0, stream>>>(
        x, w1, b1, w2, b2, w4, b4, C1, C2, C4);

    for (int s0 = 0; s0 < Sz; s0 += h) {
        int rlo = s0 - 2; if (rlo < 0) rlo = 0;
        int rhi = s0 + h + 2; if (rhi > Sz) rhi = Sz;
        int nv = rhi - rlo;                      // valid rows incl. halo

        dim3 g1(Sz / 64, (nv + 63) / 64, Bz);
        // G = x[rlo:rhi] @ x^T   (NT)
        gemm_kernel<true, false><<<g1, 256, 0, stream>>>(
            x + (size_t)rlo * Dz, x, nullptr, Gb,
            nv, Sz, Dz, (long)SD, (long)SD, (long)PS, 0);
        // A = C1[rlo:rhi] @ C2^T (NT)
        gemm_kernel<true, false><<<g1, 256, 0, stream>>>(
            C1 + (size_t)rlo * Dz, C2, nullptr, Ab,
            nv, Sz, Dz, (long)SD, (long)SD, (long)PS, 0);

        int ne = nv * Sz;
        softmax_b_kernel<<<(ne + 255) / 256, 256, 0, stream>>>(Gb, ne, (long)PS);
        softmax_b_kernel<<<(ne + 255) / 256, 256, 0, stream>>>(Ab, ne, (long)PS);

        moca_kernel<<<dim3(Sz / 256, h, Bz), 256, 0, stream>>>(
            Gb, Ab, w3, b3, Mb, s0, rlo, (long)PS, (long)PSM);

        // Wz = M @ C4 + x   (NN)
        dim3 g2(Dz / 64, h / 64, Bz);
        gemm_kernel<false, true><<<g2, 256, 0, stream>>>(
            Mb, C4, x + (size_t)s0 * Dz, out + (size_t)s0 * Dz,
            h, Dz, Sz, (long)PSM, (long)SD, (long)SD, (long)SD);
    }
}

// Round 2
// 2044.754 us; speedup vs baseline: 2.0788x; 2.0788x over previous
//
// MoCA fused pipeline — round 2: MFMA bf16 GEMMs (split-precision for softmax logits).
#include <hip/hip_runtime.h>

#define Bz 8
#define Sz 2048
#define Dz 1024

typedef __attribute__((ext_vector_type(8))) short bf16x8;
typedef __attribute__((ext_vector_type(4))) short short4v;
typedef __attribute__((ext_vector_type(4))) float f32x4;

__device__ __forceinline__ short f2b(float f) {
    unsigned u = __float_as_uint(f);
    unsigned r = (u + 0x7fffu + ((u >> 16) & 1u)) >> 16;
    return (short)r;
}

// split f into hi bf16 (truncated) + lo bf16 (rounded residual)
__device__ __forceinline__ void cvt8(const float* f, bf16x8& h8, bf16x8& l8) {
#pragma unroll
    for (int i = 0; i < 8; i++) {
        unsigned u = __float_as_uint(f[i]);
        h8[i] = (short)(u >> 16);
        float r = f[i] - __uint_as_float(u & 0xffff0000u);
        unsigned ur = __float_as_uint(r);
        l8[i] = (short)((ur + 0x8000u) >> 16);
    }
}

// ---------------- fused 5x5 convs over x ----------------
// C1[s,d]=conv(w1)+b1 (fp32), C2[s,d]=conv(w2^T)+b2 (fp32), C4[s,d]=conv(w4)+b4 (bf16)
__global__ __launch_bounds__(256) void conv3_kernel(
    const float* __restrict__ x,
    const float* __restrict__ w1, const float* __restrict__ b1,
    const float* __restrict__ w2, const float* __restrict__ b2,
    const float* __restrict__ w4, const float* __restrict__ b4,
    float* __restrict__ C1, float* __restrict__ C2, short* __restrict__ C4b)
{
    __shared__ float xs[5][1032];
    __shared__ float w[75];
    __shared__ float bias[3];
    const size_t SD = (size_t)Sz * Dz;
    int tid = threadIdx.x;
    if (tid < 25) w[tid] = w1[tid];
    else if (tid < 50) w[tid] = w2[tid - 25];
    else if (tid < 75) w[tid] = w4[tid - 50];
    if (tid == 75) { bias[0] = b1[0]; bias[1] = b2[0]; bias[2] = b4[0]; }

    int s = blockIdx.y, b = blockIdx.z;
    const float* xb = x + (size_t)b * SD;
#pragma unroll
    for (int i = 0; i < 5; i++) {
        int ss = s + i - 2;
        float4 v = make_float4(0.f, 0.f, 0.f, 0.f);
        if (ss >= 0 && ss < Sz) v = *(const float4*)(xb + (size_t)ss * Dz + tid * 4);
        *(float4*)&xs[i][4 + tid * 4] = v;
    }
    if (tid < 20) {  // zero cols -2,-1,1024,1025 (offs 2,3,1028,1029)
        int r = tid >> 2, c = tid & 3;
        xs[r][(c < 2) ? (2 + c) : (1026 + c)] = 0.f;
    }
    __syncthreads();

    int d = tid * 4;
    float o1[4] = {}, o2[4] = {}, o4[4] = {};
#pragma unroll
    for (int i = 0; i < 5; i++) {
        float wv[12];
        *(float4*)&wv[0] = *(float4*)&xs[i][d];
        *(float4*)&wv[4] = *(float4*)&xs[i][d + 4];
        *(float4*)&wv[8] = *(float4*)&xs[i][d + 8];
#pragma unroll
        for (int j = 0; j < 5; j++) {
            float c1w = w[i * 5 + j], c2w = w[25 + j * 5 + i], c4w = w[50 + i * 5 + j];
#pragma unroll
            for (int q = 0; q < 4; q++) {
                float v = wv[q + j + 2];
                o1[q] = fmaf(c1w, v, o1[q]);
                o2[q] = fmaf(c2w, v, o2[q]);
                o4[q] = fmaf(c4w, v, o4[q]);
            }
        }
    }
    size_t o = (size_t)b * SD + (size_t)s * Dz + d;
    float4 r1 = make_float4(o1[0] + bias[0], o1[1] + bias[0], o1[2] + bias[0], o1[3] + bias[0]);
    float4 r2 = make_float4(o2[0] + bias[1], o2[1] + bias[1], o2[2] + bias[1], o2[3] + bias[1]);
    *(float4*)(C1 + o) = r1;
    *(float4*)(C2 + o) = r2;
    short4v r4;
    r4[0] = f2b(o4[0] + bias[2]); r4[1] = f2b(o4[1] + bias[2]);
    r4[2] = f2b(o4[2] + bias[2]); r4[3] = f2b(o4[3] + bias[2]);
    *(short4v*)(C4b + o) = r4;
}

// ---------------- bf16 transpose: C4b[s,d] -> C4T[d,s] ----------------
__global__ __launch_bounds__(256) void transpose_bf16(
    const short* __restrict__ in, short* __restrict__ outT)
{
    __shared__ short tl[64][72];
    const size_t SD = (size_t)Sz * Dz;
    int b = blockIdx.z;
    int d0 = blockIdx.x * 64, s0 = blockIdx.y * 64;
    const short* ib = in + (size_t)b * SD;
    short* ob = outT + (size_t)b * SD;
    int t = threadIdx.x;
    int rr = t >> 3, c8 = (t & 7) * 8;
#pragma unroll
    for (int p = 0; p < 2; p++) {
        int r = rr + p * 32;
        bf16x8 v = *(const bf16x8*)(ib + (size_t)(s0 + r) * Dz + d0 + c8);
#pragma unroll
        for (int j = 0; j < 8; j++) tl[c8 + j][r] = v[j];
    }
    __syncthreads();
#pragma unroll
    for (int p = 0; p < 2; p++) {
        int r = rr + p * 32;
        bf16x8 v = *(const bf16x8*)&tl[r][c8];
        *(bf16x8*)(ob + (size_t)(d0 + r) * Sz + s0 + c8) = v;
    }
}

// ---------------- MFMA NT GEMM ----------------
// C[m,n] = sum_k A[m,k]*B[n,k] (+Src[m,n] if ADD).  SPLIT: A,B fp32, split-bf16 3-MFMA.
// !SPLIT: A,B bf16. Tile 128x128, BK=32 elems, 256 thr = 4 waves (2x2), 64x64/wave.
template <bool SPLIT, bool ADD>
__global__ __launch_bounds__(256) void gemm_mfma(
    const void* __restrict__ Ap, const void* __restrict__ Bp,
    const float* __restrict__ Src, float* __restrict__ C,
    int M, int N, int K,
    long sAb, long sBb, long sCb, long sSb)
{
    __shared__ short lds[SPLIT ? 4 : 2][128 * 32];
    short* Ah = lds[0];
    short* Bh = lds[1];
    short* Al = SPLIT ? lds[2] : lds[0];
    short* Bl = SPLIT ? lds[3] : lds[1];

    const int bz = blockIdx.z;
    const float* Agf = (const float*)Ap + (size_t)bz * sAb;
    const float* Bgf = (const float*)Bp + (size_t)bz * sBb;
    const short* Ags = (const short*)Ap + (size_t)bz * sAb;
    const short* Bgs = (const short*)Bp + (size_t)bz * sBb;
    C += (size_t)bz * sCb;
    if (ADD) Src += (size_t)bz * sSb;

    const int m0 = blockIdx.y * 128, n0 = blockIdx.x * 128;
    const int t = threadIdx.x;
    const int srow = t >> 1;            // staging row 0..127
    const int scb = (t & 1) * 16;       // staging col base (elems)
    const int lane = t & 63;
    const int w = t >> 6;
    const int wm = w >> 1, wn = w & 1;
    const int fr = lane & 15;           // frag row/col
    const int kb = lane >> 4;           // k-block 0..3

    f32x4 acc[4][4];
#pragma unroll
    for (int i = 0; i < 4; i++)
#pragma unroll
        for (int j = 0; j < 4; j++) acc[i][j] = (f32x4){0.f, 0.f, 0.f, 0.f};

    int ar = m0 + srow; if (ar >= M) ar = M - 1;
    int br = n0 + srow;                 // N is always a multiple of 128

    for (int k0 = 0; k0 < K; k0 += 32) {
        if constexpr (SPLIT) {
            float fa[16], fb[16];
            const float* ap = Agf + (size_t)ar * K + k0 + scb;
            const float* bp = Bgf + (size_t)br * K + k0 + scb;
            *(float4*)&fa[0]  = *(const float4*)(ap);
            *(float4*)&fa[4]  = *(const float4*)(ap + 4);
            *(float4*)&fa[8]  = *(const float4*)(ap + 8);
            *(float4*)&fa[12] = *(const float4*)(ap + 12);
            *(float4*)&fb[0]  = *(const float4*)(bp);
            *(float4*)&fb[4]  = *(const float4*)(bp + 4);
            *(float4*)&fb[8]  = *(const float4*)(bp + 8);
            *(float4*)&fb[12] = *(const float4*)(bp + 12);
            __syncthreads();
#pragma unroll
            for (int g = 0; g < 2; g++) {
                int kb2 = (t & 1) * 2 + g;
                int sl = kb2 ^ ((srow >> 1) & 3);
                bf16x8 h8, l8;
                cvt8(&fa[g * 8], h8, l8);
                *(bf16x8*)&Ah[srow * 32 + sl * 8] = h8;
                *(bf16x8*)&Al[srow * 32 + sl * 8] = l8;
                cvt8(&fb[g * 8], h8, l8);
                *(bf16x8*)&Bh[srow * 32 + sl * 8] = h8;
                *(bf16x8*)&Bl[srow * 32 + sl * 8] = l8;
            }
        } else {
            const short* ap = Ags + (size_t)ar * K + k0 + scb;
            const short* bp = Bgs + (size_t)br * K + k0 + scb;
            bf16x8 a0 = *(const bf16x8*)(ap);
            bf16x8 a1 = *(const bf16x8*)(ap + 8);
            bf16x8 b0 = *(const bf16x8*)(bp);
            bf16x8 b1 = *(const bf16x8*)(bp + 8);
            __syncthreads();
            int kb0 = (t & 1) * 2;
            int sw = (srow >> 1) & 3;
            *(bf16x8*)&Ah[srow * 32 + (kb0 ^ sw) * 8] = a0;
            *(bf16x8*)&Ah[srow * 32 + ((kb0 + 1) ^ sw) * 8] = a1;
            *(bf16x8*)&Bh[srow * 32 + (kb0 ^ sw) * 8] = b0;
            *(bf16x8*)&Bh[srow * 32 + ((kb0 + 1) ^ sw) * 8] = b1;
        }
        __syncthreads();

        bf16x8 ah[4], al[4], bh[4], bl[4];
#pragma unroll
        for (int f = 0; f < 4; f++) {
            int rowA = wm * 64 + f * 16 + fr;
            int slA = kb ^ ((rowA >> 1) & 3);
            ah[f] = *(bf16x8*)&Ah[rowA * 32 + slA * 8];
            if (SPLIT) al[f] = *(bf16x8*)&Al[rowA * 32 + slA * 8];
            int rowB = wn * 64 + f * 16 + fr;
            int slB = kb ^ ((rowB >> 1) & 3);
            bh[f] = *(bf16x8*)&Bh[rowB * 32 + slB * 8];
            if (SPLIT) bl[f] = *(bf16x8*)&Bl[rowB * 32 + slB * 8];
        }
#pragma unroll
        for (int mf = 0; mf < 4; mf++)
#pragma unroll
            for (int nf = 0; nf < 4; nf++) {
                acc[mf][nf] = __builtin_amdgcn_mfma_f32_16x16x32_bf16(ah[mf], bh[nf], acc[mf][nf], 0, 0, 0);
                if constexpr (SPLIT) {
                    acc[mf][nf] = __builtin_amdgcn_mfma_f32_16x16x32_bf16(ah[mf], bl[nf], acc[mf][nf], 0, 0, 0);
                    acc[mf][nf] = __builtin_amdgcn_mfma_f32_16x16x32_bf16(al[mf], bh[nf], acc[mf][nf], 0, 0, 0);
                }
            }
    }

#pragma unroll
    for (int mf = 0; mf < 4; mf++)
#pragma unroll
        for (int nf = 0; nf < 4; nf++) {
            int col = n0 + wn * 64 + nf * 16 + fr;
#pragma unroll
            for (int r = 0; r < 4; r++) {
                int rowg = m0 + wm * 64 + mf * 16 + kb * 4 + r;
                if (rowg < M) {
                    float o = acc[mf][nf][r];
                    if (ADD) o += Src[(size_t)rowg * N + col];
                    C[(size_t)rowg * N + col] = o;
                }
            }
        }
}

// ---------------- softmax over batch dim (8 planes) ----------------
__global__ __launch_bounds__(256) void softmax_b_kernel(
    float* __restrict__ P, int nElem, long planeStride)
{
    int idx = blockIdx.x * 256 + threadIdx.x;
    if (idx >= nElem) return;
    float v[Bz];
    float mx = -1e30f;
#pragma unroll
    for (int b = 0; b < Bz; b++) { v[b] = P[idx + (size_t)b * planeStride]; mx = fmaxf(mx, v[b]); }
    float sum = 0.f;
#pragma unroll
    for (int b = 0; b < Bz; b++) { v[b] = __expf(v[b] - mx); sum += v[b]; }
    float inv = 1.f / sum;
#pragma unroll
    for (int b = 0; b < Bz; b++) P[idx + (size_t)b * planeStride] = v[b] * inv;
}

// ---------------- moca 5x5 conv over {G_sm, A_sm} strip -> bf16 ----------------
__global__ __launch_bounds__(256) void moca_kernel(
    const float* __restrict__ Gs, const float* __restrict__ Asm,
    const float* __restrict__ w3, const float* __restrict__ b3,
    short* __restrict__ Mout,
    int s0, int rlo, long psIn, long psOut)
{
    __shared__ float w[50];
    __shared__ float bb;
    int tid = threadIdx.x;
    if (tid < 50) w[tid] = w3[tid];
    if (tid == 50) bb = b3[0];
    __syncthreads();

    int t4 = (blockIdx.x * 256 + tid) * 4;
    int so = blockIdx.y;
    int b = blockIdx.z;
    int s = s0 + so;
    const float* Gp = Gs + (size_t)b * psIn;
    const float* Ap = Asm + (size_t)b * psIn;

    float acc[4] = { bb, bb, bb, bb };
#pragma unroll
    for (int i = 0; i < 5; i++) {
        int sr = s + i - 2;
        if (sr < 0 || sr >= Sz) continue;
        size_t ro = (size_t)(sr - rlo) * Sz;
        float gw[12], aw[12];
#pragma unroll
        for (int c = 0; c < 3; c++) {
            int c0 = t4 - 4 + c * 4;
            if (c0 >= 0 && c0 + 3 < Sz) {
                *(float4*)&gw[c * 4] = *(const float4*)(Gp + ro + c0);
                *(float4*)&aw[c * 4] = *(const float4*)(Ap + ro + c0);
            } else {
#pragma unroll
                for (int e = 0; e < 4; e++) {
                    int cc = c0 + e;
                    bool v = (cc >= 0 && cc < Sz);
                    gw[c * 4 + e] = v ? Gp[ro + cc] : 0.f;
                    aw[c * 4 + e] = v ? Ap[ro + cc] : 0.f;
                }
            }
        }
#pragma unroll
        for (int j = 0; j < 5; j++) {
            float wg = w[i * 5 + j], wa = w[25 + i * 5 + j];
#pragma unroll
            for (int q = 0; q < 4; q++)
                acc[q] = fmaf(wg, gw[q + j + 2], fmaf(wa, aw[q + j + 2], acc[q]));
        }
    }
    short4v r;
    r[0] = f2b(acc[0]); r[1] = f2b(acc[1]); r[2] = f2b(acc[2]); r[3] = f2b(acc[3]);
    *(short4v*)(Mout + (size_t)b * psOut + (size_t)so * Sz + t4) = r;
}

// ---------------- host ----------------
extern "C" void kernel_launch(void* const* d_in, const int* in_sizes, int n_in,
                              void* d_out, int out_size, void* d_ws, size_t ws_size,
                              hipStream_t stream)
{
    const float* x  = (const float*)d_in[0];
    const float* w1 = (const float*)d_in[1];
    const float* b1 = (const float*)d_in[2];
    const float* w2 = (const float*)d_in[3];
    const float* b2 = (const float*)d_in[4];
    const float* w3 = (const float*)d_in[5];
    const float* b3 = (const float*)d_in[6];
    const float* w4 = (const float*)d_in[7];
    const float* b4 = (const float*)d_in[8];
    float* out = (float*)d_out;

    const size_t SD = (size_t)Sz * Dz;
    char* ws = (char*)d_ws;
    float* C1  = (float*)ws;                       // fp32 [B,S,D]
    float* C2  = C1 + (size_t)Bz * SD;             // fp32 [B,S,D]
    short* C4b = (short*)(C2 + (size_t)Bz * SD);   // bf16 [B,S,D]
    short* C4T = C4b + (size_t)Bz * SD;            // bf16 [B,D,S]
    char* strip0 = (char*)(C4T + (size_t)Bz * SD);
    const size_t fixedB = (size_t)(2 * 4 + 2 * 2) * Bz * SD;

    const int hs[6] = { 2048, 1020, 508, 252, 124, 60 };
    int h = 60;
    for (int i = 0; i < 6; i++) {
        size_t PS = (size_t)(hs[i] + 4) * Sz;
        size_t need = fixedB + (size_t)Bz * (2 * PS * 4 + (size_t)hs[i] * Sz * 2);
        if (need <= ws_size) { h = hs[i]; break; }
    }
    const size_t PS  = (size_t)(h + 4) * Sz;       // fp32 elems / plane (G, A)
    const size_t PSM = (size_t)h * Sz;             // bf16 elems / plane (M)
    float* Gb = (float*)strip0;
    float* Ab = Gb + (size_t)Bz * PS;
    short* Mb = (short*)(Ab + (size_t)Bz * PS);

    conv3_kernel<<<dim3(1, Sz, Bz), 256, 0, stream>>>(
        x, w1, b1, w2, b2, w4, b4, C1, C2, C4b);
    transpose_bf16<<<dim3(Dz / 64, Sz / 64, Bz), 256, 0, stream>>>(C4b, C4T);

    for (int s0 = 0; s0 < Sz; s0 += h) {
        int hcur = (Sz - s0 < h) ? (Sz - s0) : h;
        int rlo = s0 - 2; if (rlo < 0) rlo = 0;
        int rhi = s0 + hcur + 2; if (rhi > Sz) rhi = Sz;
        int nv = rhi - rlo;

        dim3 g1(Sz / 128, (nv + 127) / 128, Bz);
        gemm_mfma<true, false><<<g1, 256, 0, stream>>>(
            x + (size_t)rlo * Dz, x, nullptr, Gb,
            nv, Sz, Dz, (long)SD, (long)SD, (long)PS, 0);
        gemm_mfma<true, false><<<g1, 256, 0, stream>>>(
            C1 + (size_t)rlo * Dz, C2, nullptr, Ab,
            nv, Sz, Dz, (long)SD, (long)SD, (long)PS, 0);

        int ne = nv * Sz;
        softmax_b_kernel<<<(ne + 255) / 256, 256, 0, stream>>>(Gb, ne, (long)PS);
        softmax_b_kernel<<<(ne + 255) / 256, 256, 0, stream>>>(Ab, ne, (long)PS);

        moca_kernel<<<dim3(Sz / 1024, hcur, Bz), 256, 0, stream>>>(
            Gb, Ab, w3, b3, Mb, s0, rlo, (long)PS, (long)PSM);

        dim3 g2(Dz / 128, (hcur + 127) / 128, Bz);
        gemm_mfma<false, true><<<g2, 256, 0, stream>>>(
            Mb, C4T, x + (size_t)s0 * Dz, out + (size_t)s0 * Dz,
            hcur, Dz, Sz, (long)PSM, (long)SD, (long)SD, (long)SD);
    }
}